// Round 1
// baseline (615.138 us; speedup 1.0000x reference)
//
#include <hip/hip_runtime.h>
#include <cstdint>
#include <cstddef>

typedef __bf16 bf16;
typedef __bf16 bf16x4 __attribute__((ext_vector_type(4)));
typedef __bf16 bf16x8 __attribute__((ext_vector_type(8)));
typedef float  f32x4  __attribute__((ext_vector_type(4)));

#define HIDDEN 2048
#define NHEADS 16
#define HDIM   128
#define BSZ    2
#define SEQ    2048
#define BS     (BSZ*SEQ)     /* 4096 rows */
#define QKVN   (3*HIDDEN)    /* 6144 */

// async global->LDS, 16B per lane. LDS dest = wave-uniform base + lane*16.
__device__ __forceinline__ void async16(const bf16* g, bf16* l) {
    __builtin_amdgcn_global_load_lds(
        (const __attribute__((address_space(1))) unsigned int*)g,
        (__attribute__((address_space(3))) unsigned int*)l, 16, 0, 0);
}

// ---------------------------------------------------------------- cast fp32->bf16
__global__ __launch_bounds__(256) void cast4_kernel(const float* __restrict__ src,
                                                    bf16* __restrict__ dst, int n4) {
    int i = blockIdx.x * 256 + threadIdx.x;
    if (i < n4) {
        const float4 v = ((const float4*)src)[i];
        bf16x4 o;
        o.x = (bf16)v.x; o.y = (bf16)v.y; o.z = (bf16)v.z; o.w = (bf16)v.w;
        ((bf16x4*)dst)[i] = o;
    }
}

// ---------------------------------------------------------------- GEMM: C = A * Bt^T
// A [M,K] row-major bf16, Bt [N,K] row-major bf16, C [M,N] OutT.
// 128x128 tile, BK=32, 256 threads (4 waves, 2x2 of 64x64), 16x16x32 MFMA.
template <typename OutT>
__global__ __launch_bounds__(256) void gemm_bt(const bf16* __restrict__ A,
                                               const bf16* __restrict__ Bt,
                                               OutT* __restrict__ C,
                                               int M, int N, int K) {
    __shared__ bf16 Als[128 * 32];
    __shared__ bf16 Bls[128 * 32];
    const int tid  = threadIdx.x;
    const int lane = tid & 63;
    const int w    = tid >> 6;
    const int l15  = lane & 15;
    const int quad = lane >> 4;
    const int mTile = blockIdx.y * 128;
    const int nTile = blockIdx.x * 128;
    const int wm = (w >> 1) * 64;
    const int wn = (w & 1) * 64;

    f32x4 acc[4][4];
#pragma unroll
    for (int i = 0; i < 4; ++i)
#pragma unroll
        for (int j = 0; j < 4; ++j) acc[i][j] = (f32x4){0.f, 0.f, 0.f, 0.f};

    // staging: 8 chunks of 16 rows x 32 cols each for A and B; wave w owns chunks 2w,2w+1
    const bf16* gA = A + (size_t)(mTile + w * 32 + (lane >> 2)) * K + (lane & 3) * 8;
    const bf16* gB = Bt + (size_t)(nTile + w * 32 + (lane >> 2)) * K + (lane & 3) * 8;
    bf16* lA = Als + (w * 2) * 512;
    bf16* lB = Bls + (w * 2) * 512;

    for (int k0 = 0; k0 < K; k0 += 32) {
        async16(gA + k0,          lA);
        async16(gA + 16 * K + k0, lA + 512);
        async16(gB + k0,          lB);
        async16(gB + 16 * K + k0, lB + 512);
        __syncthreads();

        bf16x8 af[4], bfr[4];
#pragma unroll
        for (int mi = 0; mi < 4; ++mi)
            af[mi] = *(const bf16x8*)(Als + (wm + mi * 16 + l15) * 32 + quad * 8);
#pragma unroll
        for (int ni = 0; ni < 4; ++ni)
            bfr[ni] = *(const bf16x8*)(Bls + (wn + ni * 16 + l15) * 32 + quad * 8);
#pragma unroll
        for (int mi = 0; mi < 4; ++mi)
#pragma unroll
            for (int ni = 0; ni < 4; ++ni)
                acc[mi][ni] = __builtin_amdgcn_mfma_f32_16x16x32_bf16(
                    af[mi], bfr[ni], acc[mi][ni], 0, 0, 0);
        __syncthreads();
    }

    // C/D layout: col = lane&15, row = quad*4 + r
#pragma unroll
    for (int mi = 0; mi < 4; ++mi)
#pragma unroll
        for (int ni = 0; ni < 4; ++ni)
#pragma unroll
            for (int r = 0; r < 4; ++r) {
                int row = mTile + wm + mi * 16 + quad * 4 + r;
                int col = nTile + wn + ni * 16 + l15;
                C[(size_t)row * N + col] = (OutT)acc[mi][ni][r];
            }
}

// ---------------------------------------------------------------- RoPE in-place on Q,K
__global__ __launch_bounds__(256) void rope_kernel(bf16* __restrict__ qkv,
                                                   const int* __restrict__ pos_ids) {
    int idx  = blockIdx.x * 256 + threadIdx.x;   // 8,388,608 threads
    int pair = idx & 63;
    int head = (idx >> 6) & 15;
    int qk   = (idx >> 10) & 1;
    int row  = idx >> 11;                        // 0..4095
    int s    = row & (SEQ - 1);
    float p  = (float)pos_ids[s];
    // inv_freq = 10000^(-2*pair/128); ln(10000)=9.210340371976184
    float inv = expf(-(float)(2 * pair) * (9.2103403719761836f / 128.0f));
    float ang = p * inv;
    float sn, cs;
    sincosf(ang, &sn, &cs);
    size_t base = (size_t)row * QKVN + qk * HIDDEN + head * HDIM + pair;
    float x1 = (float)qkv[base];
    float x2 = (float)qkv[base + 64];
    qkv[base]      = (bf16)(x1 * cs - x2 * sn);
    qkv[base + 64] = (bf16)(x2 * cs + x1 * sn);
}

// ---------------------------------------------------------------- flash attention
// grid: 1024 blocks = (b,h) x 32 q-tiles of 64 rows. 256 threads = 4 waves,
// wave w owns q rows [qbase+16w, qbase+16w+16). K-tiles of 64 keys.
__global__ __launch_bounds__(256) void attn_kernel(const bf16* __restrict__ qkv,
                                                   bf16* __restrict__ ao) {
    __shared__ bf16 Kls[64 * 128];   // [j][d]
    __shared__ bf16 Vt[128 * 64];    // [d][j]  (V transposed)
    __shared__ bf16 Pls[4 * 16 * 64];

    const int tid  = threadIdx.x;
    const int lane = tid & 63;
    const int w    = tid >> 6;
    const int l15  = lane & 15;
    const int quad = lane >> 4;
    const int bid  = blockIdx.x;
    const int qt   = 31 - (bid >> 5);   // longest blocks dispatch first
    const int bh   = bid & 31;
    const int b    = bh >> 4;
    const int h    = bh & 15;
    const int qbase = qt * 64;
    const size_t rowb = (size_t)b * SEQ * QKVN;

    // Q fragments (A-layout: m=l15, k=quad*8+j), rows qbase+16w+l15
    bf16x8 qf[4];
    {
        const bf16* qp = qkv + rowb + (size_t)(qbase + w * 16 + l15) * QKVN + h * HDIM + quad * 8;
#pragma unroll
        for (int ks = 0; ks < 4; ++ks) qf[ks] = *(const bf16x8*)(qp + ks * 32);
    }

    f32x4 o[8];
#pragma unroll
    for (int i = 0; i < 8; ++i) o[i] = (f32x4){0.f, 0.f, 0.f, 0.f};
    float m_r[4] = {-3e38f, -3e38f, -3e38f, -3e38f};
    float l_r[4] = {0.f, 0.f, 0.f, 0.f};

    for (int t = 0; t <= qt; ++t) {
        const int kb = t * 64;
        // stage K tile [64][128] via async lds; wave w -> chunks 4w..4w+3 (4 rows each)
        {
            const bf16* kp = qkv + rowb + (size_t)(kb + w * 16 + quad) * QKVN + HIDDEN + h * HDIM + l15 * 8;
#pragma unroll
            for (int i = 0; i < 4; ++i)
                async16(kp + (size_t)(i * 4) * QKVN, Kls + (w * 4 + i) * 512);
        }
        // stage V transposed: Vt[d][j] = V[j][d]
#pragma unroll
        for (int i = 0; i < 4; ++i) {
            int vid = i * 256 + tid;
            int j   = vid >> 4;
            int d0  = (vid & 15) * 8;
            bf16x8 v = *(const bf16x8*)(qkv + rowb + (size_t)(kb + j) * QKVN + 2 * HIDDEN + h * HDIM + d0);
#pragma unroll
            for (int e = 0; e < 8; ++e) Vt[(d0 + e) * 64 + j] = v[e];
        }
        __syncthreads();

        // S = Q K^T (per wave: 16 x 64), C-layout: col j = l15(+16ni), row = quad*4+r
        f32x4 sa[4];
#pragma unroll
        for (int ni = 0; ni < 4; ++ni) sa[ni] = (f32x4){0.f, 0.f, 0.f, 0.f};
#pragma unroll
        for (int ni = 0; ni < 4; ++ni)
#pragma unroll
            for (int ks = 0; ks < 4; ++ks) {
                bf16x8 kf = *(const bf16x8*)(Kls + (ni * 16 + l15) * 128 + ks * 32 + quad * 8);
                sa[ni] = __builtin_amdgcn_mfma_f32_16x16x32_bf16(qf[ks], kf, sa[ni], 0, 0, 0);
            }

        const float scale = 0.08838834764831845f;  // 1/sqrt(128)
        float rmax[4] = {-3e38f, -3e38f, -3e38f, -3e38f};
        const bool diag = (t == qt);
#pragma unroll
        for (int ni = 0; ni < 4; ++ni) {
            int jg = kb + ni * 16 + l15;
#pragma unroll
            for (int r = 0; r < 4; ++r) {
                float sv = sa[ni][r] * scale;
                if (diag) {
                    int qg = qbase + w * 16 + quad * 4 + r;
                    if (jg > qg) sv = -1e30f;
                }
                sa[ni][r] = sv;
                rmax[r] = fmaxf(rmax[r], sv);
            }
        }
        // row max across the quad's 16 lanes (rows are quad-private)
#pragma unroll
        for (int off = 1; off < 16; off <<= 1)
#pragma unroll
            for (int r = 0; r < 4; ++r) rmax[r] = fmaxf(rmax[r], __shfl_xor(rmax[r], off));

        float alpha[4];
#pragma unroll
        for (int r = 0; r < 4; ++r) {
            float mn = fmaxf(m_r[r], rmax[r]);
            alpha[r] = __expf(m_r[r] - mn);
            m_r[r] = mn;
        }
        float rsum[4];
#pragma unroll
        for (int ni = 0; ni < 4; ++ni)
#pragma unroll
            for (int r = 0; r < 4; ++r) sa[ni][r] = __expf(sa[ni][r] - m_r[r]);
#pragma unroll
        for (int r = 0; r < 4; ++r) rsum[r] = sa[0][r] + sa[1][r] + sa[2][r] + sa[3][r];
#pragma unroll
        for (int off = 1; off < 16; off <<= 1)
#pragma unroll
            for (int r = 0; r < 4; ++r) rsum[r] += __shfl_xor(rsum[r], off);
#pragma unroll
        for (int r = 0; r < 4; ++r) l_r[r] = l_r[r] * alpha[r] + rsum[r];
#pragma unroll
        for (int n2 = 0; n2 < 8; ++n2)
#pragma unroll
            for (int r = 0; r < 4; ++r) o[n2][r] *= alpha[r];

        // P: C-layout -> LDS -> A-layout frags (per-wave region, in-wave ordering ok)
        bf16* pw = Pls + w * 1024;
#pragma unroll
        for (int ni = 0; ni < 4; ++ni)
#pragma unroll
            for (int r = 0; r < 4; ++r)
                pw[(quad * 4 + r) * 64 + ni * 16 + l15] = (bf16)sa[ni][r];
        bf16x8 pf0 = *(const bf16x8*)(pw + l15 * 64 + quad * 8);
        bf16x8 pf1 = *(const bf16x8*)(pw + l15 * 64 + 32 + quad * 8);

        // O += P V  (B from Vt: B[k=j][n=d] = Vt[d][j] rows)
#pragma unroll
        for (int n2 = 0; n2 < 8; ++n2) {
            bf16x8 vf0 = *(const bf16x8*)(Vt + (n2 * 16 + l15) * 64 + quad * 8);
            bf16x8 vf1 = *(const bf16x8*)(Vt + (n2 * 16 + l15) * 64 + 32 + quad * 8);
            o[n2] = __builtin_amdgcn_mfma_f32_16x16x32_bf16(pf0, vf0, o[n2], 0, 0, 0);
            o[n2] = __builtin_amdgcn_mfma_f32_16x16x32_bf16(pf1, vf1, o[n2], 0, 0, 0);
        }
        __syncthreads();
    }

#pragma unroll
    for (int r = 0; r < 4; ++r) l_r[r] = 1.0f / l_r[r];
    bf16* op = ao + (size_t)(b * SEQ + qbase + w * 16 + quad * 4) * HIDDEN + h * HDIM + l15;
#pragma unroll
    for (int n2 = 0; n2 < 8; ++n2)
#pragma unroll
        for (int r = 0; r < 4; ++r)
            op[(size_t)r * HIDDEN + n2 * 16] = (bf16)(o[n2][r] * l_r[r]);
}

// ---------------------------------------------------------------- launch
extern "C" void kernel_launch(void* const* d_in, const int* in_sizes, int n_in,
                              void* d_out, int out_size, void* d_ws, size_t ws_size,
                              hipStream_t stream) {
    const float* hs = (const float*)d_in[0];
    const float* Wq = (const float*)d_in[1];
    const float* Wk = (const float*)d_in[2];
    const float* Wv = (const float*)d_in[3];
    const float* Wo = (const float*)d_in[4];
    const int* pos  = (const int*)d_in[6];
    float* out = (float*)d_out;

    bf16* hs_b = (bf16*)d_ws;                               // 8,388,608 el
    bf16* wqkv = hs_b + (size_t)BS * HIDDEN;                // 12,582,912 el
    bf16* wo_b = wqkv + (size_t)QKVN * HIDDEN;              // 4,194,304 el
    bf16* qkv  = wo_b + (size_t)HIDDEN * HIDDEN;            // 25,165,824 el
    bf16* ao   = qkv + (size_t)BS * QKVN;                   // 8,388,608 el
    // total ws use: 117,440,512 bytes

    cast4_kernel<<<8192, 256, 0, stream>>>(hs, hs_b, BS * HIDDEN / 4);
    cast4_kernel<<<4096, 256, 0, stream>>>(Wq, wqkv, HIDDEN * HIDDEN / 4);
    cast4_kernel<<<4096, 256, 0, stream>>>(Wk, wqkv + (size_t)HIDDEN * HIDDEN, HIDDEN * HIDDEN / 4);
    cast4_kernel<<<4096, 256, 0, stream>>>(Wv, wqkv + (size_t)2 * HIDDEN * HIDDEN, HIDDEN * HIDDEN / 4);
    cast4_kernel<<<4096, 256, 0, stream>>>(Wo, wo_b, HIDDEN * HIDDEN / 4);

    gemm_bt<bf16><<<dim3(QKVN / 128, BS / 128), 256, 0, stream>>>(hs_b, wqkv, qkv, BS, QKVN, HIDDEN);
    rope_kernel<<<32768, 256, 0, stream>>>(qkv, pos);
    attn_kernel<<<1024, 256, 0, stream>>>(qkv, ao);
    gemm_bt<float><<<dim3(HIDDEN / 128, BS / 128), 256, 0, stream>>>(ao, wo_b, out, BS, HIDDEN, HIDDEN);
}

// Round 2
// 476.210 us; speedup vs baseline: 1.2917x; 1.2917x over previous
//
#include <hip/hip_runtime.h>
#include <cstdint>
#include <cstddef>

typedef __bf16 bf16;
typedef __bf16 bf16x4 __attribute__((ext_vector_type(4)));
typedef __bf16 bf16x8 __attribute__((ext_vector_type(8)));
typedef float  f32x4  __attribute__((ext_vector_type(4)));

#define HIDDEN 2048
#define NHEADS 16
#define HDIM   128
#define BSZ    2
#define SEQ    2048
#define BS     (BSZ*SEQ)     /* 4096 rows */
#define QKW    (2*HIDDEN)    /* 4096: Q|K concat width */

// async global->LDS, 16B per lane. LDS dest = wave-uniform base + lane*16.
__device__ __forceinline__ void async16(const bf16* g, bf16* l) {
    __builtin_amdgcn_global_load_lds(
        (const __attribute__((address_space(1))) unsigned int*)g,
        (__attribute__((address_space(3))) unsigned int*)l, 16, 0, 0);
}

// ---------------------------------------------------------------- cast fp32->bf16
__global__ __launch_bounds__(256) void cast4_kernel(const float* __restrict__ src,
                                                    bf16* __restrict__ dst, int n4) {
    int i = blockIdx.x * 256 + threadIdx.x;
    if (i < n4) {
        const float4 v = ((const float4*)src)[i];
        bf16x4 o;
        o.x = (bf16)v.x; o.y = (bf16)v.y; o.z = (bf16)v.z; o.w = (bf16)v.w;
        ((bf16x4*)dst)[i] = o;
    }
}

// ---------------------------------------------------------------- GEMM: C = A * Bt^T
// A [M,K] row-major bf16, Bt [N,K] row-major bf16, C [M,N] OutT.
// 128x128 tile, BK=32, 256 threads (4 waves, 2x2 of 64x64), 16x16x32 MFMA. (m97)
template <typename OutT>
__global__ __launch_bounds__(256) void gemm_bt(const bf16* __restrict__ A,
                                               const bf16* __restrict__ Bt,
                                               OutT* __restrict__ C,
                                               int M, int N, int K) {
    __shared__ bf16 Als[128 * 32];
    __shared__ bf16 Bls[128 * 32];
    const int tid  = threadIdx.x;
    const int lane = tid & 63;
    const int w    = tid >> 6;
    const int l15  = lane & 15;
    const int quad = lane >> 4;
    const int mTile = blockIdx.y * 128;
    const int nTile = blockIdx.x * 128;
    const int wm = (w >> 1) * 64;
    const int wn = (w & 1) * 64;

    f32x4 acc[4][4];
#pragma unroll
    for (int i = 0; i < 4; ++i)
#pragma unroll
        for (int j = 0; j < 4; ++j) acc[i][j] = (f32x4){0.f, 0.f, 0.f, 0.f};

    const bf16* gA = A + (size_t)(mTile + w * 32 + (lane >> 2)) * K + (lane & 3) * 8;
    const bf16* gB = Bt + (size_t)(nTile + w * 32 + (lane >> 2)) * K + (lane & 3) * 8;
    bf16* lA = Als + (w * 2) * 512;
    bf16* lB = Bls + (w * 2) * 512;

    for (int k0 = 0; k0 < K; k0 += 32) {
        async16(gA + k0,          lA);
        async16(gA + 16 * K + k0, lA + 512);
        async16(gB + k0,          lB);
        async16(gB + 16 * K + k0, lB + 512);
        __syncthreads();

        bf16x8 af[4], bfr[4];
#pragma unroll
        for (int mi = 0; mi < 4; ++mi)
            af[mi] = *(const bf16x8*)(Als + (wm + mi * 16 + l15) * 32 + quad * 8);
#pragma unroll
        for (int ni = 0; ni < 4; ++ni)
            bfr[ni] = *(const bf16x8*)(Bls + (wn + ni * 16 + l15) * 32 + quad * 8);
#pragma unroll
        for (int mi = 0; mi < 4; ++mi)
#pragma unroll
            for (int ni = 0; ni < 4; ++ni)
                acc[mi][ni] = __builtin_amdgcn_mfma_f32_16x16x32_bf16(
                    af[mi], bfr[ni], acc[mi][ni], 0, 0, 0);
        __syncthreads();
    }

#pragma unroll
    for (int mi = 0; mi < 4; ++mi)
#pragma unroll
        for (int ni = 0; ni < 4; ++ni)
#pragma unroll
            for (int r = 0; r < 4; ++r) {
                int row = mTile + wm + mi * 16 + quad * 4 + r;
                int col = nTile + wn + ni * 16 + l15;
                C[(size_t)row * N + col] = (OutT)acc[mi][ni][r];
            }
}

// ---------------------------------------------------------------- RoPE in-place on Q,K (qk buffer [4096][4096])
__global__ __launch_bounds__(256) void rope_kernel(bf16* __restrict__ qk,
                                                   const int* __restrict__ pos_ids) {
    int idx  = blockIdx.x * 256 + threadIdx.x;   // 8,388,608 threads
    int pair = idx & 63;
    int head = (idx >> 6) & 15;
    int qkb  = (idx >> 10) & 1;
    int row  = idx >> 11;                        // 0..4095
    int s    = row & (SEQ - 1);
    float p  = (float)pos_ids[s];
    float inv = expf(-(float)(2 * pair) * (9.2103403719761836f / 128.0f));
    float ang = p * inv;
    float sn, cs;
    sincosf(ang, &sn, &cs);
    size_t base = (size_t)row * QKW + qkb * HIDDEN + head * HDIM + pair;
    float x1 = (float)qk[base];
    float x2 = (float)qk[base + 64];
    qk[base]      = (bf16)(x1 * cs - x2 * sn);
    qk[base + 64] = (bf16)(x2 * cs + x1 * sn);
}

// ---------------------------------------------------------------- flash attention
// qk: [4096][4096] rows=token, cols: [0,2048)=Q, [2048,4096)=K (post-RoPE)
// vt: [2048][4096] rows = h*128+d, cols = token  (V^T, from swapped GEMM)
// grid: 1024 blocks = (b,h) x 32 q-tiles of 64 rows; 256 thr = 4 waves,
// wave w owns q rows [qbase+16w, qbase+16w+16). K-tiles of 64 keys.
// All LDS tiles XOR-swizzled: chunk c of row j stored at c ^ (j&7) (16B chunks).
__global__ __launch_bounds__(256) void attn_kernel(const bf16* __restrict__ qk,
                                                   const bf16* __restrict__ vt,
                                                   bf16* __restrict__ ao) {
    __shared__ bf16 Kls[64 * 128];   // [j][d], 16 chunks/row, swizzled
    __shared__ bf16 Vls[128 * 64];   // [d][s], 8 chunks/row, swizzled
    __shared__ bf16 Pls[4 * 16 * 64];// per-wave [m][j], 8 chunks/row, swizzled

    const int tid  = threadIdx.x;
    const int lane = tid & 63;
    const int w    = tid >> 6;
    const int l15  = lane & 15;
    const int quad = lane >> 4;
    const int l7   = lane & 7;
    const int bid  = blockIdx.x;
    const int qt   = 31 - (bid >> 5);   // longest blocks dispatch first
    const int bh   = bid & 31;
    const int b    = bh >> 4;
    const int h    = bh & 15;
    const int qbase = qt * 64;
    const size_t seq0 = (size_t)b * SEQ;

    // Q fragments (B/A layout: m=l15, k=quad*8+j)
    bf16x8 qf[4];
    {
        const bf16* qp = qk + (seq0 + qbase + w * 16 + l15) * QKW + h * HDIM + quad * 8;
#pragma unroll
        for (int ks = 0; ks < 4; ++ks) qf[ks] = *(const bf16x8*)(qp + ks * 32);
    }

    f32x4 o[8];
#pragma unroll
    for (int i = 0; i < 8; ++i) o[i] = (f32x4){0.f, 0.f, 0.f, 0.f};
    float m_r[4] = {-3e38f, -3e38f, -3e38f, -3e38f};
    float l_r[4] = {0.f, 0.f, 0.f, 0.f};

    const int krow = lane >> 4;   // K staging: 4 rows/async16, chunk = lane&15
    const int kp   = lane & 15;
    const int vrow = lane >> 3;   // V staging: 8 rows/async16, chunk = lane&7
    const int vp   = lane & 7;
    const int sw   = l15 & 7;     // read-side swizzle key (row&7 == l15&7 everywhere)

    for (int t = 0; t <= qt; ++t) {
        const int kb = t * 64;
        // ---- stage K tile [64][128] swizzled: LDS[j][p] = global chunk p^(j&7)
#pragma unroll
        for (int i = 0; i < 4; ++i) {
            int j = w * 16 + i * 4 + krow;
            int c = (kp & 8) | ((kp & 7) ^ (j & 7));
            async16(qk + (seq0 + kb + j) * QKW + HIDDEN + h * HDIM + c * 8,
                    Kls + (w * 4 + i) * 512);
        }
        // ---- stage V^T tile [128][64] swizzled: LDS[d][p] = global chunk p^(d&7)
#pragma unroll
        for (int i = 0; i < 4; ++i) {
            int d = w * 32 + i * 8 + vrow;
            int c = vp ^ (d & 7);
            async16(vt + (size_t)(h * HDIM + d) * (size_t)BS + seq0 + kb + c * 8,
                    Vls + (w * 4 + i) * 512);
        }
        __syncthreads();

        // ---- S = Q K^T (per wave: 16 x 64), C-layout: col=l15(+16ni), row=quad*4+r
        f32x4 sa[4];
#pragma unroll
        for (int ni = 0; ni < 4; ++ni) sa[ni] = (f32x4){0.f, 0.f, 0.f, 0.f};
#pragma unroll
        for (int ni = 0; ni < 4; ++ni)
#pragma unroll
            for (int ks = 0; ks < 4; ++ks) {
                bf16x8 kf = *(const bf16x8*)(Kls + (ni * 16 + l15) * 128 +
                                             (((ks * 4 + quad) ^ sw) << 3));
                sa[ni] = __builtin_amdgcn_mfma_f32_16x16x32_bf16(qf[ks], kf, sa[ni], 0, 0, 0);
            }

        const float scale = 0.08838834764831845f;  // 1/sqrt(128)
        float rmax[4] = {-3e38f, -3e38f, -3e38f, -3e38f};
        const bool diag = (t == qt);
#pragma unroll
        for (int ni = 0; ni < 4; ++ni) {
            int jg = kb + ni * 16 + l15;
#pragma unroll
            for (int r = 0; r < 4; ++r) {
                float sv = sa[ni][r] * scale;
                if (diag) {
                    int qg = qbase + w * 16 + quad * 4 + r;
                    if (jg > qg) sv = -1e30f;
                }
                sa[ni][r] = sv;
                rmax[r] = fmaxf(rmax[r], sv);
            }
        }
#pragma unroll
        for (int off = 1; off < 16; off <<= 1)
#pragma unroll
            for (int r = 0; r < 4; ++r) rmax[r] = fmaxf(rmax[r], __shfl_xor(rmax[r], off));

        float alpha[4];
#pragma unroll
        for (int r = 0; r < 4; ++r) {
            float mn = fmaxf(m_r[r], rmax[r]);
            alpha[r] = __expf(m_r[r] - mn);
            m_r[r] = mn;
        }
        float rsum[4];
#pragma unroll
        for (int ni = 0; ni < 4; ++ni)
#pragma unroll
            for (int r = 0; r < 4; ++r) sa[ni][r] = __expf(sa[ni][r] - m_r[r]);
#pragma unroll
        for (int r = 0; r < 4; ++r) rsum[r] = sa[0][r] + sa[1][r] + sa[2][r] + sa[3][r];
#pragma unroll
        for (int off = 1; off < 16; off <<= 1)
#pragma unroll
            for (int r = 0; r < 4; ++r) rsum[r] += __shfl_xor(rsum[r], off);
#pragma unroll
        for (int r = 0; r < 4; ++r) l_r[r] = l_r[r] * alpha[r] + rsum[r];
#pragma unroll
        for (int n2 = 0; n2 < 8; ++n2)
#pragma unroll
            for (int r = 0; r < 4; ++r) o[n2][r] *= alpha[r];

        // ---- P: C-layout -> swizzled LDS -> A-layout frags (per-wave region)
        bf16* pw = Pls + w * 1024;
#pragma unroll
        for (int ni = 0; ni < 4; ++ni)
#pragma unroll
            for (int r = 0; r < 4; ++r) {
                int row = quad * 4 + r;
                int cc  = ni * 2 + (l15 >> 3);            // logical chunk of col
                pw[row * 64 + (((cc ^ (row & 7)) << 3) | l7)] = (bf16)sa[ni][r];
            }
        bf16x8 pf0 = *(const bf16x8*)(pw + l15 * 64 + (((quad    ) ^ sw) << 3));
        bf16x8 pf1 = *(const bf16x8*)(pw + l15 * 64 + (((quad + 4) ^ sw) << 3));

        // ---- O += P V   (B from Vls rows: lane l15 = d, k = j contiguous)
#pragma unroll
        for (int n2 = 0; n2 < 8; ++n2) {
            bf16x8 vf0 = *(const bf16x8*)(Vls + (n2 * 16 + l15) * 64 + (((quad    ) ^ sw) << 3));
            bf16x8 vf1 = *(const bf16x8*)(Vls + (n2 * 16 + l15) * 64 + (((quad + 4) ^ sw) << 3));
            o[n2] = __builtin_amdgcn_mfma_f32_16x16x32_bf16(pf0, vf0, o[n2], 0, 0, 0);
            o[n2] = __builtin_amdgcn_mfma_f32_16x16x32_bf16(pf1, vf1, o[n2], 0, 0, 0);
        }
        __syncthreads();
    }

#pragma unroll
    for (int r = 0; r < 4; ++r) l_r[r] = 1.0f / l_r[r];
    bf16* op = ao + (seq0 + qbase + w * 16 + quad * 4) * HIDDEN + h * HDIM + l15;
#pragma unroll
    for (int n2 = 0; n2 < 8; ++n2)
#pragma unroll
        for (int r = 0; r < 4; ++r)
            op[(size_t)r * HIDDEN + n2 * 16] = (bf16)(o[n2][r] * l_r[r]);
}

// ---------------------------------------------------------------- launch
extern "C" void kernel_launch(void* const* d_in, const int* in_sizes, int n_in,
                              void* d_out, int out_size, void* d_ws, size_t ws_size,
                              hipStream_t stream) {
    const float* hs = (const float*)d_in[0];
    const float* Wq = (const float*)d_in[1];
    const float* Wk = (const float*)d_in[2];
    const float* Wv = (const float*)d_in[3];
    const float* Wo = (const float*)d_in[4];
    const int* pos  = (const int*)d_in[6];
    float* out = (float*)d_out;

    bf16* hs_b = (bf16*)d_ws;                               //  8,388,608 el
    bf16* wqk  = hs_b + (size_t)BS * HIDDEN;                //  8,388,608 el (Wq|Wk rows)
    bf16* wv_b = wqk + (size_t)QKW * HIDDEN;                //  4,194,304 el
    bf16* wo_b = wv_b + (size_t)HIDDEN * HIDDEN;            //  4,194,304 el
    bf16* qkb  = wo_b + (size_t)HIDDEN * HIDDEN;            // 16,777,216 el  [4096][4096]
    bf16* vtb  = qkb + (size_t)BS * QKW;                    //  8,388,608 el  [2048][4096]
    bf16* ao   = vtb + (size_t)HIDDEN * BS;                 //  8,388,608 el
    // total: 58,720,256 el = 117,440,512 B

    cast4_kernel<<<8192, 256, 0, stream>>>(hs, hs_b, BS * HIDDEN / 4);
    cast4_kernel<<<4096, 256, 0, stream>>>(Wq, wqk, HIDDEN * HIDDEN / 4);
    cast4_kernel<<<4096, 256, 0, stream>>>(Wk, wqk + (size_t)HIDDEN * HIDDEN, HIDDEN * HIDDEN / 4);
    cast4_kernel<<<4096, 256, 0, stream>>>(Wv, wv_b, HIDDEN * HIDDEN / 4);
    cast4_kernel<<<4096, 256, 0, stream>>>(Wo, wo_b, HIDDEN * HIDDEN / 4);

    // qk = hs @ [Wq|Wk]^T   [4096][4096]
    gemm_bt<bf16><<<dim3(QKW / 128, BS / 128), 256, 0, stream>>>(hs_b, wqk, qkb, BS, QKW, HIDDEN);
    // vt = Wv @ hs^T = V^T  [2048][4096]  (swapped operands => transposed output, free)
    gemm_bt<bf16><<<dim3(BS / 128, HIDDEN / 128), 256, 0, stream>>>(wv_b, hs_b, vtb, HIDDEN, BS, HIDDEN);
    rope_kernel<<<32768, 256, 0, stream>>>(qkb, pos);
    attn_kernel<<<1024, 256, 0, stream>>>(qkb, vtb, ao);
    gemm_bt<float><<<dim3(HIDDEN / 128, BS / 128), 256, 0, stream>>>(ao, wo_b, out, BS, HIDDEN, HIDDEN);
}

// Round 3
// 418.747 us; speedup vs baseline: 1.4690x; 1.1372x over previous
//
#include <hip/hip_runtime.h>
#include <cstdint>
#include <cstddef>

typedef __bf16 bf16;
typedef __bf16 bf16x4 __attribute__((ext_vector_type(4)));
typedef __bf16 bf16x8 __attribute__((ext_vector_type(8)));
typedef float  f32x4  __attribute__((ext_vector_type(4)));

#define HIDDEN 2048
#define NHEADS 16
#define HDIM   128
#define BSZ    2
#define SEQ    2048
#define BS     (BSZ*SEQ)     /* 4096 rows */
#define QKW    (2*HIDDEN)    /* 4096: Q|K concat width */

// async global->LDS, 16B per lane. LDS dest = wave-uniform base + lane*16.
__device__ __forceinline__ void async16(const bf16* g, bf16* l) {
    __builtin_amdgcn_global_load_lds(
        (const __attribute__((address_space(1))) unsigned int*)g,
        (__attribute__((address_space(3))) unsigned int*)l, 16, 0, 0);
}

// ---------------------------------------------------------------- fused casts
// regions (float4 units): hs 2^21 | Wq 2^20 | Wk 2^20 | Wv 2^20 | Wo 2^20
__global__ __launch_bounds__(256) void cast_all(const float* __restrict__ hs,
                                                const float* __restrict__ Wq,
                                                const float* __restrict__ Wk,
                                                const float* __restrict__ Wv,
                                                const float* __restrict__ Wo,
                                                bf16* __restrict__ hs_b,
                                                bf16* __restrict__ wqkv,
                                                bf16* __restrict__ wo_b) {
    int i = blockIdx.x * 256 + threadIdx.x;   // 6,291,456 total
    const float* src; bf16* dst; int off;
    if (i < 2097152) { src = hs; dst = hs_b; off = i; }
    else {
        int j = i - 2097152;
        int r = j >> 20;
        off = j & 1048575;
        if      (r == 0) { src = Wq; dst = wqkv; }
        else if (r == 1) { src = Wk; dst = wqkv + (size_t)4194304; }
        else if (r == 2) { src = Wv; dst = wqkv + (size_t)8388608; }
        else             { src = Wo; dst = wo_b; }
    }
    const float4 v = ((const float4*)src)[off];
    bf16x4 o;
    o.x = (bf16)v.x; o.y = (bf16)v.y; o.z = (bf16)v.z; o.w = (bf16)v.w;
    ((bf16x4*)dst)[off] = o;
}

// ---------------------------------------------------------------- rope cos/sin table [2048][64] float2
__global__ __launch_bounds__(256) void rope_table(const int* __restrict__ pos,
                                                  float2* __restrict__ tab) {
    int i = blockIdx.x * 256 + threadIdx.x;   // 131072
    int s = i >> 6, p = i & 63;
    float t = (float)pos[s];
    float inv = expf(-(float)(2 * p) * (9.2103403719761836f / 128.0f));
    float sn, cs;
    sincosf(t * inv, &sn, &cs);
    tab[i] = make_float2(cs, sn);
}

// ---------------------------------------------------------------- fused QKV GEMM + RoPE + V^T
// A=hs_b [4096][2048], Bt=wqkv [6144][2048]. grid (48,32), 256 thr.
// Wave n-cols retiled so col d and d^64 share a lane: coloff(ni) = wv*32+(ni&1)*16+(ni>>1)*64.
// nTile<4096: RoPE'd store to qk [4096][4096]. nTile>=4096: transposed store to vt [2048][4096].
__global__ __launch_bounds__(256) void gemm_qkv(const bf16* __restrict__ A,
                                                const bf16* __restrict__ Bt,
                                                const float2* __restrict__ tab,
                                                bf16* __restrict__ qk,
                                                bf16* __restrict__ vtb) {
    __shared__ bf16 Als[128 * 32];
    __shared__ bf16 Bls[128 * 32];
    const int K    = HIDDEN;
    const int tid  = threadIdx.x;
    const int lane = tid & 63;
    const int w    = tid >> 6;
    const int l15  = lane & 15;
    const int quad = lane >> 4;
    const int mTile = blockIdx.y * 128;
    const int nTile = blockIdx.x * 128;
    const int wm = (w >> 1) * 64;
    const int wv = w & 1;

    f32x4 acc[4][4];
#pragma unroll
    for (int i = 0; i < 4; ++i)
#pragma unroll
        for (int j = 0; j < 4; ++j) acc[i][j] = (f32x4){0.f, 0.f, 0.f, 0.f};

    const bf16* gA = A + (size_t)(mTile + w * 32 + (lane >> 2)) * K + (lane & 3) * 8;
    const bf16* gB = Bt + (size_t)(nTile + w * 32 + (lane >> 2)) * K + (lane & 3) * 8;
    bf16* lA = Als + w * 1024;
    bf16* lB = Bls + w * 1024;

    for (int k0 = 0; k0 < K; k0 += 32) {
        async16(gA + k0,          lA);
        async16(gA + 16 * K + k0, lA + 512);
        async16(gB + k0,          lB);
        async16(gB + 16 * K + k0, lB + 512);
        __syncthreads();

        bf16x8 af[4], bfr[4];
#pragma unroll
        for (int mi = 0; mi < 4; ++mi)
            af[mi] = *(const bf16x8*)(Als + (wm + mi * 16 + l15) * 32 + quad * 8);
#pragma unroll
        for (int ni = 0; ni < 4; ++ni) {
            int co = wv * 32 + (ni & 1) * 16 + (ni >> 1) * 64;
            bfr[ni] = *(const bf16x8*)(Bls + (co + l15) * 32 + quad * 8);
        }
#pragma unroll
        for (int mi = 0; mi < 4; ++mi)
#pragma unroll
            for (int ni = 0; ni < 4; ++ni)
                acc[mi][ni] = __builtin_amdgcn_mfma_f32_16x16x32_bf16(
                    af[mi], bfr[ni], acc[mi][ni], 0, 0, 0);
        __syncthreads();
    }

    if (nTile < QKW) {
        // RoPE epilogue: acc[ni] (d<64 half) pairs with acc[ni+2] (d>=64 half), same lane
#pragma unroll
        for (int mi = 0; mi < 4; ++mi)
#pragma unroll
            for (int r = 0; r < 4; ++r) {
                int row = mTile + wm + mi * 16 + quad * 4 + r;
                int s   = row & (SEQ - 1);
                float2 t0 = tab[s * 64 + wv * 32 + l15];
                float2 t1 = tab[s * 64 + wv * 32 + 16 + l15];
                size_t rb = (size_t)row * QKW + nTile + wv * 32 + l15;
                float lo0 = acc[mi][0][r], hi0 = acc[mi][2][r];
                float lo1 = acc[mi][1][r], hi1 = acc[mi][3][r];
                qk[rb]      = (bf16)(lo0 * t0.x - hi0 * t0.y);
                qk[rb + 64] = (bf16)(hi0 * t0.x + lo0 * t0.y);
                qk[rb + 16] = (bf16)(lo1 * t1.x - hi1 * t1.y);
                qk[rb + 80] = (bf16)(hi1 * t1.x + lo1 * t1.y);
            }
    } else {
        // V region: store transposed, vt[feature][token], 8B column segments
#pragma unroll
        for (int mi = 0; mi < 4; ++mi)
#pragma unroll
            for (int ni = 0; ni < 4; ++ni) {
                int col_v = (nTile - QKW) + wv * 32 + (ni & 1) * 16 + (ni >> 1) * 64 + l15;
                int row0  = mTile + wm + mi * 16 + quad * 4;
                bf16x4 pk;
#pragma unroll
                for (int r = 0; r < 4; ++r) pk[r] = (bf16)acc[mi][ni][r];
                *(bf16x4*)(vtb + (size_t)col_v * BS + row0) = pk;
            }
    }
}

// ---------------------------------------------------------------- GEMM: C = A * Bt^T (final proj)
template <typename OutT>
__global__ __launch_bounds__(256) void gemm_bt(const bf16* __restrict__ A,
                                               const bf16* __restrict__ Bt,
                                               OutT* __restrict__ C,
                                               int M, int N, int K) {
    __shared__ bf16 Als[128 * 32];
    __shared__ bf16 Bls[128 * 32];
    const int tid  = threadIdx.x;
    const int lane = tid & 63;
    const int w    = tid >> 6;
    const int l15  = lane & 15;
    const int quad = lane >> 4;
    const int mTile = blockIdx.y * 128;
    const int nTile = blockIdx.x * 128;
    const int wm = (w >> 1) * 64;
    const int wn = (w & 1) * 64;

    f32x4 acc[4][4];
#pragma unroll
    for (int i = 0; i < 4; ++i)
#pragma unroll
        for (int j = 0; j < 4; ++j) acc[i][j] = (f32x4){0.f, 0.f, 0.f, 0.f};

    const bf16* gA = A + (size_t)(mTile + w * 32 + (lane >> 2)) * K + (lane & 3) * 8;
    const bf16* gB = Bt + (size_t)(nTile + w * 32 + (lane >> 2)) * K + (lane & 3) * 8;
    bf16* lA = Als + w * 1024;
    bf16* lB = Bls + w * 1024;

    for (int k0 = 0; k0 < K; k0 += 32) {
        async16(gA + k0,          lA);
        async16(gA + 16 * K + k0, lA + 512);
        async16(gB + k0,          lB);
        async16(gB + 16 * K + k0, lB + 512);
        __syncthreads();

        bf16x8 af[4], bfr[4];
#pragma unroll
        for (int mi = 0; mi < 4; ++mi)
            af[mi] = *(const bf16x8*)(Als + (wm + mi * 16 + l15) * 32 + quad * 8);
#pragma unroll
        for (int ni = 0; ni < 4; ++ni)
            bfr[ni] = *(const bf16x8*)(Bls + (wn + ni * 16 + l15) * 32 + quad * 8);
#pragma unroll
        for (int mi = 0; mi < 4; ++mi)
#pragma unroll
            for (int ni = 0; ni < 4; ++ni)
                acc[mi][ni] = __builtin_amdgcn_mfma_f32_16x16x32_bf16(
                    af[mi], bfr[ni], acc[mi][ni], 0, 0, 0);
        __syncthreads();
    }

#pragma unroll
    for (int mi = 0; mi < 4; ++mi)
#pragma unroll
        for (int ni = 0; ni < 4; ++ni)
#pragma unroll
            for (int r = 0; r < 4; ++r) {
                int row = mTile + wm + mi * 16 + quad * 4 + r;
                int col = nTile + wn + ni * 16 + l15;
                C[(size_t)row * N + col] = (OutT)acc[mi][ni][r];
            }
}

// ---------------------------------------------------------------- flash attention
// qk: [4096][4096] rows=token, cols [0,2048)=Q, [2048,4096)=K (RoPE'd)
// vt: [2048][4096] rows=feature (h*128+d), cols=token
// grid 1024 = (b,h) x 32 q-tiles of 64; 4 waves, wave w owns q rows [qbase+16w,+16).
// LDS XOR-swizzled (16B chunk c of row j at c^(j&7)). Softmax in exp2 domain.
__global__ __launch_bounds__(256) void attn_kernel(const bf16* __restrict__ qk,
                                                   const bf16* __restrict__ vt,
                                                   bf16* __restrict__ ao) {
    __shared__ bf16 Kls[64 * 128];
    __shared__ bf16 Vls[128 * 64];
    __shared__ bf16 Pls[4 * 16 * 64];

    const int tid  = threadIdx.x;
    const int lane = tid & 63;
    const int w    = tid >> 6;
    const int l15  = lane & 15;
    const int quad = lane >> 4;
    const int l7   = lane & 7;
    const int bid  = blockIdx.x;
    const int qt   = 31 - (bid >> 5);   // longest blocks dispatch first
    const int bh   = bid & 31;
    const int b    = bh >> 4;
    const int h    = bh & 15;
    const int qbase = qt * 64;
    const size_t seq0 = (size_t)b * SEQ;

    bf16x8 qf[4];
    {
        const bf16* qp = qk + (seq0 + qbase + w * 16 + l15) * QKW + h * HDIM + quad * 8;
#pragma unroll
        for (int ks = 0; ks < 4; ++ks) qf[ks] = *(const bf16x8*)(qp + ks * 32);
    }

    f32x4 o[8];
#pragma unroll
    for (int i = 0; i < 8; ++i) o[i] = (f32x4){0.f, 0.f, 0.f, 0.f};
    float m_r[4] = {-3e38f, -3e38f, -3e38f, -3e38f};
    float l_r[4] = {0.f, 0.f, 0.f, 0.f};

    const int krow = lane >> 4;
    const int kp   = lane & 15;
    const int vrow = lane >> 3;
    const int vp   = lane & 7;
    const int sw   = l15 & 7;

    for (int t = 0; t <= qt; ++t) {
        const int kb = t * 64;
#pragma unroll
        for (int i = 0; i < 4; ++i) {
            int j = w * 16 + i * 4 + krow;
            int c = (kp & 8) | ((kp & 7) ^ (j & 7));
            async16(qk + (seq0 + kb + j) * QKW + HIDDEN + h * HDIM + c * 8,
                    Kls + (w * 4 + i) * 512);
        }
#pragma unroll
        for (int i = 0; i < 4; ++i) {
            int d = w * 32 + i * 8 + vrow;
            int c = vp ^ (d & 7);
            async16(vt + (size_t)(h * HDIM + d) * (size_t)BS + seq0 + kb + c * 8,
                    Vls + (w * 4 + i) * 512);
        }
        __syncthreads();

        f32x4 sa[4];
#pragma unroll
        for (int ni = 0; ni < 4; ++ni) sa[ni] = (f32x4){0.f, 0.f, 0.f, 0.f};
#pragma unroll
        for (int ni = 0; ni < 4; ++ni)
#pragma unroll
            for (int ks = 0; ks < 4; ++ks) {
                bf16x8 kf = *(const bf16x8*)(Kls + (ni * 16 + l15) * 128 +
                                             (((ks * 4 + quad) ^ sw) << 3));
                sa[ni] = __builtin_amdgcn_mfma_f32_16x16x32_bf16(qf[ks], kf, sa[ni], 0, 0, 0);
            }

        // exp2-domain softmax: fold 1/sqrt(128) * log2(e) into the scale
        const float scale = 0.08838834764831845f * 1.4426950408889634f;
        float rmax[4] = {-3e38f, -3e38f, -3e38f, -3e38f};
        const bool diag = (t == qt);
#pragma unroll
        for (int ni = 0; ni < 4; ++ni) {
            int jg = kb + ni * 16 + l15;
#pragma unroll
            for (int r = 0; r < 4; ++r) {
                float sv = sa[ni][r] * scale;
                if (diag) {
                    int qg = qbase + w * 16 + quad * 4 + r;
                    if (jg > qg) sv = -1e30f;
                }
                sa[ni][r] = sv;
                rmax[r] = fmaxf(rmax[r], sv);
            }
        }
#pragma unroll
        for (int off = 1; off < 16; off <<= 1)
#pragma unroll
            for (int r = 0; r < 4; ++r) rmax[r] = fmaxf(rmax[r], __shfl_xor(rmax[r], off));

        float alpha[4];
#pragma unroll
        for (int r = 0; r < 4; ++r) {
            float mn = fmaxf(m_r[r], rmax[r]);
            alpha[r] = exp2f(m_r[r] - mn);
            m_r[r] = mn;
        }
        float rsum[4];
#pragma unroll
        for (int ni = 0; ni < 4; ++ni)
#pragma unroll
            for (int r = 0; r < 4; ++r) sa[ni][r] = exp2f(sa[ni][r] - m_r[r]);
#pragma unroll
        for (int r = 0; r < 4; ++r) rsum[r] = sa[0][r] + sa[1][r] + sa[2][r] + sa[3][r];
#pragma unroll
        for (int off = 1; off < 16; off <<= 1)
#pragma unroll
            for (int r = 0; r < 4; ++r) rsum[r] += __shfl_xor(rsum[r], off);
#pragma unroll
        for (int r = 0; r < 4; ++r) l_r[r] = l_r[r] * alpha[r] + rsum[r];

        // skip O-rescale when alpha==1 in every lane (common once max stabilizes)
        bool needscale = (alpha[0] != 1.f) | (alpha[1] != 1.f) |
                         (alpha[2] != 1.f) | (alpha[3] != 1.f);
        if (__ballot(needscale) != 0ull) {
#pragma unroll
            for (int n2 = 0; n2 < 8; ++n2)
#pragma unroll
                for (int r = 0; r < 4; ++r) o[n2][r] *= alpha[r];
        }

        bf16* pw = Pls + w * 1024;
#pragma unroll
        for (int ni = 0; ni < 4; ++ni)
#pragma unroll
            for (int r = 0; r < 4; ++r) {
                int row = quad * 4 + r;
                int cc  = ni * 2 + (l15 >> 3);
                pw[row * 64 + (((cc ^ (row & 7)) << 3) | l7)] = (bf16)sa[ni][r];
            }
        bf16x8 pf0 = *(const bf16x8*)(pw + l15 * 64 + (((quad    ) ^ sw) << 3));
        bf16x8 pf1 = *(const bf16x8*)(pw + l15 * 64 + (((quad + 4) ^ sw) << 3));

#pragma unroll
        for (int n2 = 0; n2 < 8; ++n2) {
            bf16x8 vf0 = *(const bf16x8*)(Vls + (n2 * 16 + l15) * 64 + (((quad    ) ^ sw) << 3));
            bf16x8 vf1 = *(const bf16x8*)(Vls + (n2 * 16 + l15) * 64 + (((quad + 4) ^ sw) << 3));
            o[n2] = __builtin_amdgcn_mfma_f32_16x16x32_bf16(pf0, vf0, o[n2], 0, 0, 0);
            o[n2] = __builtin_amdgcn_mfma_f32_16x16x32_bf16(pf1, vf1, o[n2], 0, 0, 0);
        }
        __syncthreads();
    }

#pragma unroll
    for (int r = 0; r < 4; ++r) l_r[r] = 1.0f / l_r[r];
    bf16* op = ao + (seq0 + qbase + w * 16 + quad * 4) * HIDDEN + h * HDIM + l15;
#pragma unroll
    for (int n2 = 0; n2 < 8; ++n2)
#pragma unroll
        for (int r = 0; r < 4; ++r)
            op[(size_t)r * HIDDEN + n2 * 16] = (bf16)(o[n2][r] * l_r[r]);
}

// ---------------------------------------------------------------- launch
extern "C" void kernel_launch(void* const* d_in, const int* in_sizes, int n_in,
                              void* d_out, int out_size, void* d_ws, size_t ws_size,
                              hipStream_t stream) {
    const float* hs = (const float*)d_in[0];
    const float* Wq = (const float*)d_in[1];
    const float* Wk = (const float*)d_in[2];
    const float* Wv = (const float*)d_in[3];
    const float* Wo = (const float*)d_in[4];
    const int* pos  = (const int*)d_in[6];
    float* out = (float*)d_out;

    bf16* hs_b = (bf16*)d_ws;                               //  8,388,608 el
    bf16* wqkv = hs_b + (size_t)8388608;                    // 12,582,912 el [6144][2048]
    bf16* wo_b = wqkv + (size_t)12582912;                   //  4,194,304 el
    bf16* qkb  = wo_b + (size_t)4194304;                    // 16,777,216 el [4096][4096]
    bf16* vtb  = qkb + (size_t)16777216;                    //  8,388,608 el [2048][4096]
    bf16* ao   = vtb + (size_t)8388608;                     //  8,388,608 el
    float2* tab = (float2*)ao;  // 1 MB, consumed by gemm_qkv BEFORE attn writes ao
    // total: 117,440,512 B

    cast_all<<<24576, 256, 0, stream>>>(hs, Wq, Wk, Wv, Wo, hs_b, wqkv, wo_b);
    rope_table<<<512, 256, 0, stream>>>(pos, tab);
    gemm_qkv<<<dim3(48, 32), 256, 0, stream>>>(hs_b, wqkv, tab, qkb, vtb);
    attn_kernel<<<1024, 256, 0, stream>>>(qkb, vtb, ao);
    gemm_bt<float><<<dim3(HIDDEN / 128, BS / 128), 256, 0, stream>>>(ao, wo_b, out, BS, HIDDEN, HIDDEN);
}

// Round 4
// 398.784 us; speedup vs baseline: 1.5425x; 1.0501x over previous
//
#include <hip/hip_runtime.h>
#include <cstdint>
#include <cstddef>

typedef __bf16 bf16;
typedef __bf16 bf16x4 __attribute__((ext_vector_type(4)));
typedef __bf16 bf16x8 __attribute__((ext_vector_type(8)));
typedef float  f32x4  __attribute__((ext_vector_type(4)));
typedef short  s16x4  __attribute__((ext_vector_type(4)));

#define HIDDEN 2048
#define NHEADS 16
#define HDIM   128
#define BSZ    2
#define SEQ    2048
#define BS     (BSZ*SEQ)     /* 4096 rows */
#define QKW    (2*HIDDEN)    /* 4096: Q|K concat width */

union b4u { bf16x4 h; s16x4 s; };

// async global->LDS, 16B per lane. LDS dest = wave-uniform base + lane*16.
__device__ __forceinline__ void async16(const bf16* g, bf16* l) {
    __builtin_amdgcn_global_load_lds(
        (const __attribute__((address_space(1))) unsigned int*)g,
        (__attribute__((address_space(3))) unsigned int*)l, 16, 0, 0);
}

// ---------------------------------------------------------------- fused casts + rope table
// blocks [0,24576): cast fp32->bf16 (hs | Wq | Wk | Wv | Wo, float4 units)
// blocks [24576,25088): rope cos/sin table [2048][64] float2
__global__ __launch_bounds__(256) void cast_all(const float* __restrict__ hs,
                                                const float* __restrict__ Wq,
                                                const float* __restrict__ Wk,
                                                const float* __restrict__ Wv,
                                                const float* __restrict__ Wo,
                                                const int* __restrict__ pos,
                                                bf16* __restrict__ hs_b,
                                                bf16* __restrict__ wqkv,
                                                bf16* __restrict__ wo_b,
                                                float2* __restrict__ tab) {
    int i = blockIdx.x * 256 + threadIdx.x;
    if (i >= 6291456) {                       // rope table region
        int j = i - 6291456;                  // 0..131071
        int s = j >> 6, p = j & 63;
        float t = (float)pos[s];
        float inv = expf(-(float)(2 * p) * (9.2103403719761836f / 128.0f));
        float sn, cs;
        sincosf(t * inv, &sn, &cs);
        tab[j] = make_float2(cs, sn);
        return;
    }
    const float* src; bf16* dst; int off;
    if (i < 2097152) { src = hs; dst = hs_b; off = i; }
    else {
        int j = i - 2097152;
        int r = j >> 20;
        off = j & 1048575;
        if      (r == 0) { src = Wq; dst = wqkv; }
        else if (r == 1) { src = Wk; dst = wqkv + (size_t)4194304; }
        else if (r == 2) { src = Wv; dst = wqkv + (size_t)8388608; }
        else             { src = Wo; dst = wo_b; }
    }
    const float4 v = ((const float4*)src)[off];
    bf16x4 o;
    o.x = (bf16)v.x; o.y = (bf16)v.y; o.z = (bf16)v.z; o.w = (bf16)v.w;
    ((bf16x4*)dst)[off] = o;
}

// ---------------------------------------------------------------- fused QKV GEMM + RoPE + V^T
// A=hs_b [4096][2048], Bt=wqkv [6144][2048]. grid (48,32), 256 thr.
// Wave n-cols retiled so col d and d^64 share a lane: coloff(ni) = wv*32+(ni&1)*16+(ni>>1)*64.
// nTile<4096: RoPE'd store to qk [4096][4096]. nTile>=4096: transposed store to vt [2048][4096].
__global__ __launch_bounds__(256) void gemm_qkv(const bf16* __restrict__ A,
                                                const bf16* __restrict__ Bt,
                                                const float2* __restrict__ tab,
                                                bf16* __restrict__ qk,
                                                bf16* __restrict__ vtb) {
    __shared__ bf16 Als[128 * 32];
    __shared__ bf16 Bls[128 * 32];
    const int K    = HIDDEN;
    const int tid  = threadIdx.x;
    const int lane = tid & 63;
    const int w    = tid >> 6;
    const int l15  = lane & 15;
    const int quad = lane >> 4;
    const int mTile = blockIdx.y * 128;
    const int nTile = blockIdx.x * 128;
    const int wm = (w >> 1) * 64;
    const int wv = w & 1;

    f32x4 acc[4][4];
#pragma unroll
    for (int i = 0; i < 4; ++i)
#pragma unroll
        for (int j = 0; j < 4; ++j) acc[i][j] = (f32x4){0.f, 0.f, 0.f, 0.f};

    const bf16* gA = A + (size_t)(mTile + w * 32 + (lane >> 2)) * K + (lane & 3) * 8;
    const bf16* gB = Bt + (size_t)(nTile + w * 32 + (lane >> 2)) * K + (lane & 3) * 8;
    bf16* lA = Als + w * 1024;
    bf16* lB = Bls + w * 1024;

    for (int k0 = 0; k0 < K; k0 += 32) {
        async16(gA + k0,          lA);
        async16(gA + 16 * K + k0, lA + 512);
        async16(gB + k0,          lB);
        async16(gB + 16 * K + k0, lB + 512);
        __syncthreads();

        bf16x8 af[4], bfr[4];
#pragma unroll
        for (int mi = 0; mi < 4; ++mi)
            af[mi] = *(const bf16x8*)(Als + (wm + mi * 16 + l15) * 32 + quad * 8);
#pragma unroll
        for (int ni = 0; ni < 4; ++ni) {
            int co = wv * 32 + (ni & 1) * 16 + (ni >> 1) * 64;
            bfr[ni] = *(const bf16x8*)(Bls + (co + l15) * 32 + quad * 8);
        }
#pragma unroll
        for (int mi = 0; mi < 4; ++mi)
#pragma unroll
            for (int ni = 0; ni < 4; ++ni)
                acc[mi][ni] = __builtin_amdgcn_mfma_f32_16x16x32_bf16(
                    af[mi], bfr[ni], acc[mi][ni], 0, 0, 0);
        __syncthreads();
    }

    if (nTile < QKW) {
        // RoPE epilogue: acc[ni] (d<64 half) pairs with acc[ni+2] (d>=64 half), same lane
#pragma unroll
        for (int mi = 0; mi < 4; ++mi)
#pragma unroll
            for (int r = 0; r < 4; ++r) {
                int row = mTile + wm + mi * 16 + quad * 4 + r;
                int s   = row & (SEQ - 1);
                float2 t0 = tab[s * 64 + wv * 32 + l15];
                float2 t1 = tab[s * 64 + wv * 32 + 16 + l15];
                size_t rb = (size_t)row * QKW + nTile + wv * 32 + l15;
                float lo0 = acc[mi][0][r], hi0 = acc[mi][2][r];
                float lo1 = acc[mi][1][r], hi1 = acc[mi][3][r];
                qk[rb]      = (bf16)(lo0 * t0.x - hi0 * t0.y);
                qk[rb + 64] = (bf16)(hi0 * t0.x + lo0 * t0.y);
                qk[rb + 16] = (bf16)(lo1 * t1.x - hi1 * t1.y);
                qk[rb + 80] = (bf16)(hi1 * t1.x + lo1 * t1.y);
            }
    } else {
        // V region: store transposed, vt[feature][token], 8B column segments
#pragma unroll
        for (int mi = 0; mi < 4; ++mi)
#pragma unroll
            for (int ni = 0; ni < 4; ++ni) {
                int col_v = (nTile - QKW) + wv * 32 + (ni & 1) * 16 + (ni >> 1) * 64 + l15;
                int row0  = mTile + wm + mi * 16 + quad * 4;
                bf16x4 pk;
#pragma unroll
                for (int r = 0; r < 4; ++r) pk[r] = (bf16)acc[mi][ni][r];
                *(bf16x4*)(vtb + (size_t)col_v * BS + row0) = pk;
            }
    }
}

// ---------------------------------------------------------------- GEMM: C = A * Bt^T (final proj)
template <typename OutT>
__global__ __launch_bounds__(256) void gemm_bt(const bf16* __restrict__ A,
                                               const bf16* __restrict__ Bt,
                                               OutT* __restrict__ C,
                                               int M, int N, int K) {
    __shared__ bf16 Als[128 * 32];
    __shared__ bf16 Bls[128 * 32];
    const int tid  = threadIdx.x;
    const int lane = tid & 63;
    const int w    = tid >> 6;
    const int l15  = lane & 15;
    const int quad = lane >> 4;
    const int mTile = blockIdx.y * 128;
    const int nTile = blockIdx.x * 128;
    const int wm = (w >> 1) * 64;
    const int wn = (w & 1) * 64;

    f32x4 acc[4][4];
#pragma unroll
    for (int i = 0; i < 4; ++i)
#pragma unroll
        for (int j = 0; j < 4; ++j) acc[i][j] = (f32x4){0.f, 0.f, 0.f, 0.f};

    const bf16* gA = A + (size_t)(mTile + w * 32 + (lane >> 2)) * K + (lane & 3) * 8;
    const bf16* gB = Bt + (size_t)(nTile + w * 32 + (lane >> 2)) * K + (lane & 3) * 8;
    bf16* lA = Als + w * 1024;
    bf16* lB = Bls + w * 1024;

    for (int k0 = 0; k0 < K; k0 += 32) {
        async16(gA + k0,          lA);
        async16(gA + 16 * K + k0, lA + 512);
        async16(gB + k0,          lB);
        async16(gB + 16 * K + k0, lB + 512);
        __syncthreads();

        bf16x8 af[4], bfr[4];
#pragma unroll
        for (int mi = 0; mi < 4; ++mi)
            af[mi] = *(const bf16x8*)(Als + (wm + mi * 16 + l15) * 32 + quad * 8);
#pragma unroll
        for (int ni = 0; ni < 4; ++ni)
            bfr[ni] = *(const bf16x8*)(Bls + (wn + ni * 16 + l15) * 32 + quad * 8);
#pragma unroll
        for (int mi = 0; mi < 4; ++mi)
#pragma unroll
            for (int ni = 0; ni < 4; ++ni)
                acc[mi][ni] = __builtin_amdgcn_mfma_f32_16x16x32_bf16(
                    af[mi], bfr[ni], acc[mi][ni], 0, 0, 0);
        __syncthreads();
    }

#pragma unroll
    for (int mi = 0; mi < 4; ++mi)
#pragma unroll
        for (int ni = 0; ni < 4; ++ni)
#pragma unroll
            for (int r = 0; r < 4; ++r) {
                int row = mTile + wm + mi * 16 + quad * 4 + r;
                int col = nTile + wn + ni * 16 + l15;
                C[(size_t)row * N + col] = (OutT)acc[mi][ni][r];
            }
}

// ---------------------------------------------------------------- flash attention (S^T form)
// qk: [4096][4096] rows=token, cols [0,2048)=Q, [2048,4096)=K (RoPE'd)
// vt: [2048][4096] rows=feature (h*128+d), cols=token
// grid 1024 = (b,h) x 32 q-tiles of 64; 4 waves, wave w owns q rows [qbase+16w,+16).
// S^T = K·Q^T (swapped MFMA operands): C col = q-row (lane l15), row = key.
// Softmax state is lane-scalar; P^T feeds PV directly as 16x16x16 B-operand (no LDS roundtrip).
__global__ __launch_bounds__(256) void attn_kernel(const bf16* __restrict__ qk,
                                                   const bf16* __restrict__ vt,
                                                   bf16* __restrict__ ao) {
    __shared__ bf16 Kls[64 * 128];   // [j][d], 16B chunk c of row j at c^(j&7)
    __shared__ bf16 Vls[128 * 64];   // [d][s], swizzled same

    const int tid  = threadIdx.x;
    const int lane = tid & 63;
    const int w    = tid >> 6;
    const int l15  = lane & 15;
    const int quad = lane >> 4;
    const int bid  = blockIdx.x;
    const int qt   = 31 - (bid >> 5);   // longest blocks dispatch first
    const int bh   = bid & 31;
    const int b    = bh >> 4;
    const int h    = bh & 15;
    const int qbase = qt * 64;
    const size_t seq0 = (size_t)b * SEQ;

    // Q fragments (serve as B-operand: n=l15=q-row, k=quad*8+j)
    bf16x8 qf[4];
    {
        const bf16* qp = qk + (seq0 + qbase + w * 16 + l15) * QKW + h * HDIM + quad * 8;
#pragma unroll
        for (int ks = 0; ks < 4; ++ks) qf[ks] = *(const bf16x8*)(qp + ks * 32);
    }

    f32x4 o[8];   // O^T: q-row = l15, d = n2*16 + quad*4 + r
#pragma unroll
    for (int i = 0; i < 8; ++i) o[i] = (f32x4){0.f, 0.f, 0.f, 0.f};
    float m_s = -3e38f, l_s = 0.f;
    const int qg = qbase + w * 16 + l15;     // this lane's q-row (global)

    const int krow = lane >> 4;
    const int kp   = lane & 15;
    const int vrow = lane >> 3;
    const int vp   = lane & 7;
    const int sw   = l15 & 7;

    for (int t = 0; t <= qt; ++t) {
        const int kb = t * 64;
#pragma unroll
        for (int i = 0; i < 4; ++i) {
            int j = w * 16 + i * 4 + krow;
            int c = (kp & 8) | ((kp & 7) ^ (j & 7));
            async16(qk + (seq0 + kb + j) * QKW + HIDDEN + h * HDIM + c * 8,
                    Kls + (w * 4 + i) * 512);
        }
#pragma unroll
        for (int i = 0; i < 4; ++i) {
            int d = w * 32 + i * 8 + vrow;
            int c = vp ^ (d & 7);
            async16(vt + (size_t)(h * HDIM + d) * (size_t)BS + seq0 + kb + c * 8,
                    Vls + (w * 4 + i) * 512);
        }
        __syncthreads();

        // S^T = K Q^T: sa[ni] C-layout col=l15 (q-row), row=quad*4+r (key ni*16+..)
        f32x4 sa[4];
#pragma unroll
        for (int ni = 0; ni < 4; ++ni) sa[ni] = (f32x4){0.f, 0.f, 0.f, 0.f};
#pragma unroll
        for (int ni = 0; ni < 4; ++ni)
#pragma unroll
            for (int ks = 0; ks < 4; ++ks) {
                bf16x8 kf = *(const bf16x8*)(Kls + (ni * 16 + l15) * 128 +
                                             (((ks * 4 + quad) ^ sw) << 3));
                sa[ni] = __builtin_amdgcn_mfma_f32_16x16x32_bf16(kf, qf[ks], sa[ni], 0, 0, 0);
            }

        // exp2-domain softmax, lane-scalar state
        const float scale = 0.08838834764831845f * 1.4426950408889634f;
        float rmax = -3e38f;
        const bool diag = (t == qt);
#pragma unroll
        for (int ni = 0; ni < 4; ++ni)
#pragma unroll
            for (int r = 0; r < 4; ++r) {
                float sv = sa[ni][r] * scale;
                if (diag) {
                    int jg = kb + ni * 16 + quad * 4 + r;
                    if (jg > qg) sv = -1e30f;
                }
                sa[ni][r] = sv;
                rmax = fmaxf(rmax, sv);
            }
        rmax = fmaxf(rmax, __shfl_xor(rmax, 16));
        rmax = fmaxf(rmax, __shfl_xor(rmax, 32));

        float mn = fmaxf(m_s, rmax);
        float alpha = exp2f(m_s - mn);
        m_s = mn;
        float rsum = 0.f;
        b4u pb[4];
#pragma unroll
        for (int ni = 0; ni < 4; ++ni)
#pragma unroll
            for (int r = 0; r < 4; ++r) {
                float e = exp2f(sa[ni][r] - mn);
                rsum += e;
                pb[ni].h[r] = (bf16)e;
            }
        rsum += __shfl_xor(rsum, 16);
        rsum += __shfl_xor(rsum, 32);
        l_s = l_s * alpha + rsum;

        if (__ballot(alpha != 1.f) != 0ull) {
#pragma unroll
            for (int n2 = 0; n2 < 8; ++n2)
#pragma unroll
                for (int r = 0; r < 4; ++r) o[n2][r] *= alpha;
        }

        // O^T += V^T P^T : A = V^T frag (m=l15=d, k=quad*4+i=j), B = pb[ni]
#pragma unroll
        for (int n2 = 0; n2 < 8; ++n2)
#pragma unroll
            for (int ni = 0; ni < 4; ++ni) {
                b4u vf;
                vf.h = *(const bf16x4*)(Vls + (n2 * 16 + l15) * 64 +
                                        ((((ni * 2 + (quad >> 1)) ^ sw) << 3) + (quad & 1) * 4));
                o[n2] = __builtin_amdgcn_mfma_f32_16x16x16bf16_1k(vf.s, pb[ni].s, o[n2], 0, 0, 0);
            }
        __syncthreads();
    }

    const float inv = 1.0f / l_s;
    bf16* op = ao + (seq0 + qg) * HIDDEN + h * HDIM + quad * 4;
#pragma unroll
    for (int n2 = 0; n2 < 8; ++n2) {
        bf16x4 pk;
#pragma unroll
        for (int r = 0; r < 4; ++r) pk[r] = (bf16)(o[n2][r] * inv);
        *(bf16x4*)(op + n2 * 16) = pk;
    }
}

// ---------------------------------------------------------------- launch
extern "C" void kernel_launch(void* const* d_in, const int* in_sizes, int n_in,
                              void* d_out, int out_size, void* d_ws, size_t ws_size,
                              hipStream_t stream) {
    const float* hs = (const float*)d_in[0];
    const float* Wq = (const float*)d_in[1];
    const float* Wk = (const float*)d_in[2];
    const float* Wv = (const float*)d_in[3];
    const float* Wo = (const float*)d_in[4];
    const int* pos  = (const int*)d_in[6];
    float* out = (float*)d_out;

    bf16* hs_b = (bf16*)d_ws;                               //  8,388,608 el
    bf16* wqkv = hs_b + (size_t)8388608;                    // 12,582,912 el [6144][2048]
    bf16* wo_b = wqkv + (size_t)12582912;                   //  4,194,304 el
    bf16* qkb  = wo_b + (size_t)4194304;                    // 16,777,216 el [4096][4096]
    bf16* vtb  = qkb + (size_t)16777216;                    //  8,388,608 el [2048][4096]
    bf16* ao   = vtb + (size_t)8388608;                     //  8,388,608 el
    float2* tab = (float2*)ao;  // 1 MB, consumed by gemm_qkv BEFORE attn writes ao
    // total: 117,440,512 B

    cast_all<<<25088, 256, 0, stream>>>(hs, Wq, Wk, Wv, Wo, pos, hs_b, wqkv, wo_b, tab);
    gemm_qkv<<<dim3(48, 32), 256, 0, stream>>>(hs_b, wqkv, tab, qkb, vtb);
    attn_kernel<<<1024, 256, 0, stream>>>(qkb, vtb, ao);
    gemm_bt<float><<<dim3(HIDDEN / 128, BS / 128), 256, 0, stream>>>(ao, wo_b, out, BS, HIDDEN, HIDDEN);
}